// Round 20
// baseline (36.620 us; speedup 1.0000x reference)
//
#include <hip/hip_runtime.h>
#include <math.h>

// Shapes (hard-coded per reference setup_inputs):
//   b=16, t=128, c=t-1=127, kv_dim=k=64, h=4, q_dim=256
#define Bdim 16
#define Tdim 128
#define Cdim 127
#define Hdim 4
#define QD   256
#define HK   256   // h*k
#define BT   (Bdim * Tdim)

// ---- DPP quad ops (VALU pipe) ----
#define DPP_XOR1 0xB1   // quad_perm [1,0,3,2] : lane^1
#define DPP_XOR2 0x4E   // quad_perm [2,3,0,1] : lane^2
template<int CTRL>
__device__ __forceinline__ float dpp_movf(float x) {
    return __int_as_float(__builtin_amdgcn_update_dpp(
        0, __float_as_int(x), CTRL, 0xF, 0xF, true));
}
__device__ __forceinline__ float dot4(float4 a, float4 b, float s) {
    return fmaf(a.x, b.x, fmaf(a.y, b.y, fmaf(a.z, b.z, fmaf(a.w, b.w, s))));
}
__device__ __forceinline__ float4 fma4(float e, float4 x, float4 v) {
    v.x = fmaf(e, x.x, v.x); v.y = fmaf(e, x.y, v.y);
    v.z = fmaf(e, x.z, v.z); v.w = fmaf(e, x.w, v.w);
    return v;
}
__device__ __forceinline__ float4 add4(float4 a, float4 b) {
    return make_float4(a.x + b.x, a.y + b.y, a.z + b.z, a.w + b.w);
}
__device__ __forceinline__ float4 shfl4(float4 v, int m) {
    return make_float4(__shfl_xor(v.x, m, 64), __shfl_xor(v.y, m, 64),
                       __shfl_xor(v.z, m, 64), __shfl_xor(v.w, m, 64));
}
__device__ __forceinline__ float4 sel4(int c, float4 a, float4 b) {
    return c ? a : b;
}

// ---------------------------------------------------------------------------
// K1: qk[bt, h*64+m] = sum_j (q_x[bt,:] @ Wq)[h*64+j] * Wk[m, h*64+j]
// (measured ~2.4 us including launch gap — unchanged)
__global__ __launch_bounds__(256) void qk_fused(
        const float* __restrict__ q_x,
        const float* __restrict__ Wq,
        const float* __restrict__ Wk,
        float* __restrict__ qk) {
    __shared__ __align__(16) float q_s[4][256];
    __shared__ __align__(16) float p_s[4][4][68];   // [row][head][j] padded
    int RB = blockIdx.x;
    int tid = threadIdx.x;
    {
        int r = tid >> 6, kq = tid & 63;
        *(float4*)&q_s[r][kq*4] =
            *(const float4*)(q_x + (size_t)(RB*4 + r) * QD + kq * 4);
    }
    __syncthreads();

    float acc[4] = {0.f, 0.f, 0.f, 0.f};
    #pragma unroll 4
    for (int i4 = 0; i4 < 64; ++i4) {
        float w0 = Wq[(size_t)(4*i4+0) * HK + tid];   // coalesced, L2-hot
        float w1 = Wq[(size_t)(4*i4+1) * HK + tid];
        float w2 = Wq[(size_t)(4*i4+2) * HK + tid];
        float w3 = Wq[(size_t)(4*i4+3) * HK + tid];
        #pragma unroll
        for (int r = 0; r < 4; ++r) {
            float4 qv = *(const float4*)&q_s[r][i4*4];   // b128 broadcast
            acc[r] = fmaf(qv.x, w0, fmaf(qv.y, w1, fmaf(qv.z, w2, fmaf(qv.w, w3, acc[r]))));
        }
    }
    int h = tid >> 6, m = tid & 63;
    #pragma unroll
    for (int r = 0; r < 4; ++r) p_s[r][h][m] = acc[r];
    __syncthreads();

    const float4* wk4 = (const float4*)(Wk + (size_t)m * HK + h * 64);
    float4 wkr[16];
    #pragma unroll
    for (int j = 0; j < 16; ++j) wkr[j] = wk4[j];       // L2-hot, 64 KB total
    float a2[4] = {0.f, 0.f, 0.f, 0.f};
    #pragma unroll
    for (int j4 = 0; j4 < 16; ++j4) {
        #pragma unroll
        for (int r = 0; r < 4; ++r) {
            float4 pv = *(const float4*)&p_s[r][h][j4*4];  // wave-uniform bcast
            a2[r] = fmaf(pv.x, wkr[j4].x, fmaf(pv.y, wkr[j4].y,
                    fmaf(pv.z, wkr[j4].z, fmaf(pv.w, wkr[j4].w, a2[r]))));
        }
    }
    #pragma unroll
    for (int r = 0; r < 4; ++r)
        qk[(size_t)(RB*4 + r) * HK + tid] = a2[r];      // coalesced
}

// ---------------------------------------------------------------------------
// K2: attn_fused — r19's single-pass max-line-coverage core + PER-WAVE
// V-projection epilogue (vproj kernel, its launch gap, and the 4 MB
// wx/denom round-trip eliminated). Zero barriers anywhere: the epilogue
// reads wave-private LDS written by the same wave (in-order DS semantics).
// Lane map: r = lane>>2 (row-slot 0..15), jq = lane&3 (row quarter): every
// load instruction's 64 lanes hit 64 DISTINCT 64B lines (r19: this is what
// lifted delivered BW 1.85 -> ~2.3 TB/s). 3-deep A/B/C load pipeline.
__global__ __launch_bounds__(256, 2) void attn_fused(
        const float* __restrict__ kv_x,
        const float* __restrict__ qk_g,
        const float* __restrict__ Wv,
        float* __restrict__ out) {
    __shared__ __align__(16) float4 wx_s[4][64];     // [wave][chunk] 4 KB
    int tid = threadIdx.x;
    int wv = tid >> 6, lane = tid & 63;
    int bt = blockIdx.x * 4 + wv;
    int r  = lane >> 2;           // row-slot 0..15
    int jq = lane & 3;            // quarter of the row
    const float* Xr = kv_x + (size_t)bt * (Cdim * 64);

    // Q: all 4 heads' quarter jq -> 16 float4 regs (dup over r: merged)
    const float4* qb = (const float4*)(qk_g + (size_t)bt * HK);
    float4 Q00 = qb[ 0 + jq*4 + 0], Q01 = qb[ 0 + jq*4 + 1],
           Q02 = qb[ 0 + jq*4 + 2], Q03 = qb[ 0 + jq*4 + 3];
    float4 Q10 = qb[16 + jq*4 + 0], Q11 = qb[16 + jq*4 + 1],
           Q12 = qb[16 + jq*4 + 2], Q13 = qb[16 + jq*4 + 3];
    float4 Q20 = qb[32 + jq*4 + 0], Q21 = qb[32 + jq*4 + 1],
           Q22 = qb[32 + jq*4 + 2], Q23 = qb[32 + jq*4 + 3];
    float4 Q30 = qb[48 + jq*4 + 0], Q31 = qb[48 + jq*4 + 1],
           Q32 = qb[48 + jq*4 + 2], Q33 = qb[48 + jq*4 + 3];

    float4 V00={0,0,0,0},V01={0,0,0,0},V02={0,0,0,0},V03={0,0,0,0};
    float4 V10={0,0,0,0},V11={0,0,0,0},V12={0,0,0,0},V13={0,0,0,0};
    float4 V20={0,0,0,0},V21={0,0,0,0},V22={0,0,0,0},V23={0,0,0,0};
    float4 V30={0,0,0,0},V31={0,0,0,0},V32={0,0,0,0},V33={0,0,0,0};
    float d0=0.f, d1=0.f, d2=0.f, d3=0.f;
    float4 A0, A1, A2, A3, B0, B1, B2, B3, C0, C1, C2, C3;

#define LOADR(P0,P1,P2,P3,KK) do {                                           \
    int c_ = 16*(KK) + r;                                                    \
    const float4* xp_ = (const float4*)(Xr + (size_t)((c_ < Cdim) ? c_ : 0)  \
                                        * 64) + jq * 4;                      \
    P0 = xp_[0]; P1 = xp_[1]; P2 = xp_[2]; P3 = xp_[3];                      \
} while (0)

#define COMP(P0,P1,P2,P3,KK) do {                                            \
    float s0 = dot4(Q00,P0,0.f); s0 = dot4(Q01,P1,s0);                       \
    s0 = dot4(Q02,P2,s0); s0 = dot4(Q03,P3,s0);                              \
    float s1 = dot4(Q10,P0,0.f); s1 = dot4(Q11,P1,s1);                       \
    s1 = dot4(Q12,P2,s1); s1 = dot4(Q13,P3,s1);                              \
    float s2 = dot4(Q20,P0,0.f); s2 = dot4(Q21,P1,s2);                       \
    s2 = dot4(Q22,P2,s2); s2 = dot4(Q23,P3,s2);                              \
    float s3 = dot4(Q30,P0,0.f); s3 = dot4(Q31,P1,s3);                       \
    s3 = dot4(Q32,P2,s3); s3 = dot4(Q33,P3,s3);                              \
    s0 += dpp_movf<DPP_XOR1>(s0); s0 += dpp_movf<DPP_XOR2>(s0);              \
    s1 += dpp_movf<DPP_XOR1>(s1); s1 += dpp_movf<DPP_XOR2>(s1);              \
    s2 += dpp_movf<DPP_XOR1>(s2); s2 += dpp_movf<DPP_XOR2>(s2);              \
    s3 += dpp_movf<DPP_XOR1>(s3); s3 += dpp_movf<DPP_XOR2>(s3);              \
    bool vld_ = (16*(KK) + r) < Cdim;                                        \
    float e0 = vld_ ? __expf(s0 * 0.125f) : 0.f;                             \
    float e1 = vld_ ? __expf(s1 * 0.125f) : 0.f;                             \
    float e2 = vld_ ? __expf(s2 * 0.125f) : 0.f;                             \
    float e3 = vld_ ? __expf(s3 * 0.125f) : 0.f;                             \
    d0 += e0; d1 += e1; d2 += e2; d3 += e3;                                  \
    V00=fma4(e0,P0,V00); V01=fma4(e0,P1,V01);                                \
    V02=fma4(e0,P2,V02); V03=fma4(e0,P3,V03);                                \
    V10=fma4(e1,P0,V10); V11=fma4(e1,P1,V11);                                \
    V12=fma4(e1,P2,V12); V13=fma4(e1,P3,V13);                                \
    V20=fma4(e2,P0,V20); V21=fma4(e2,P1,V21);                                \
    V22=fma4(e2,P2,V22); V23=fma4(e2,P3,V23);                                \
    V30=fma4(e3,P0,V30); V31=fma4(e3,P1,V31);                                \
    V32=fma4(e3,P2,V32); V33=fma4(e3,P3,V33);                                \
} while (0)

    // 3-deep hand pipeline: 12 b128 loads in flight per lane-group
    LOADR(A0,A1,A2,A3,0);
    LOADR(B0,B1,B2,B3,1);
    LOADR(C0,C1,C2,C3,2);
    COMP (A0,A1,A2,A3,0);
    LOADR(A0,A1,A2,A3,3);
    COMP (B0,B1,B2,B3,1);
    LOADR(B0,B1,B2,B3,4);
    COMP (C0,C1,C2,C3,2);
    LOADR(C0,C1,C2,C3,5);
    COMP (A0,A1,A2,A3,3);
    LOADR(A0,A1,A2,A3,6);
    COMP (B0,B1,B2,B3,4);
    LOADR(B0,B1,B2,B3,7);
    COMP (C0,C1,C2,C3,5);
    COMP (A0,A1,A2,A3,6);
    COMP (B0,B1,B2,B3,7);
#undef LOADR
#undef COMP

    // ---- splitting butterfly over r bits (lane bits 2-5): each round
    // halves the live set; ends with ONE float4 chunk per lane ----
    int r0 = (lane >> 2) & 1, r1 = (lane >> 3) & 1;
    int r2 = (lane >> 4) & 1, r3 = (lane >> 5) & 1;
    float4 K00 = add4(sel4(r0, V01, V00), shfl4(sel4(r0, V00, V01), 4));
    float4 K01 = add4(sel4(r0, V03, V02), shfl4(sel4(r0, V02, V03), 4));
    float4 K10 = add4(sel4(r0, V11, V10), shfl4(sel4(r0, V10, V11), 4));
    float4 K11 = add4(sel4(r0, V13, V12), shfl4(sel4(r0, V12, V13), 4));
    float4 K20 = add4(sel4(r0, V21, V20), shfl4(sel4(r0, V20, V21), 4));
    float4 K21 = add4(sel4(r0, V23, V22), shfl4(sel4(r0, V22, V23), 4));
    float4 K30 = add4(sel4(r0, V31, V30), shfl4(sel4(r0, V30, V31), 4));
    float4 K31 = add4(sel4(r0, V33, V32), shfl4(sel4(r0, V32, V33), 4));
    float4 L0 = add4(sel4(r1, K01, K00), shfl4(sel4(r1, K00, K01), 8));
    float4 L1 = add4(sel4(r1, K11, K10), shfl4(sel4(r1, K10, K11), 8));
    float4 L2 = add4(sel4(r1, K21, K20), shfl4(sel4(r1, K20, K21), 8));
    float4 L3 = add4(sel4(r1, K31, K30), shfl4(sel4(r1, K30, K31), 8));
    float4 M0 = add4(sel4(r2, L1, L0), shfl4(sel4(r2, L0, L1), 16));
    float4 M1 = add4(sel4(r2, L3, L2), shfl4(sel4(r2, L2, L3), 16));
    float4 F = add4(sel4(r3, M1, M0), shfl4(sel4(r3, M0, M1), 32));

    // denom butterfly (all lanes end with the 4 head totals)
    #pragma unroll
    for (int m = 4; m <= 32; m <<= 1) {
        d0 += __shfl_xor(d0, m, 64); d1 += __shfl_xor(d1, m, 64);
        d2 += __shfl_xor(d2, m, 64); d3 += __shfl_xor(d3, m, 64);
    }

    // chunk (H, jq, qo) -> wave-private LDS (same-wave DS ordering: no
    // barrier; compiler inserts lgkmcnt before the dependent reads)
    int H  = (r3 << 1) | r2;
    int qo = (r1 << 1) | r0;
    wx_s[wv][H * 16 + jq * 4 + qo] = F;

    // ---- fused V-projection epilogue: lane -> cols {p*64+lane} ----
    {
        float inv0 = 1.f / d0, inv1 = 1.f / d1, inv2 = 1.f / d2, inv3 = 1.f / d3;
        float* obt = out + (size_t)bt * HK;
        #pragma unroll
        for (int p = 0; p < 4; ++p) {
            const float* wvc = Wv + p * 64 + lane;    // coalesced, L2-hot
            float acc = 0.f;
            #pragma unroll
            for (int j4 = 0; j4 < 16; ++j4) {
                float4 w4 = wx_s[wv][p * 16 + j4];    // same-addr broadcast
                acc = fmaf(w4.x, wvc[(size_t)(j4*4+0) * HK],
                      fmaf(w4.y, wvc[(size_t)(j4*4+1) * HK],
                      fmaf(w4.z, wvc[(size_t)(j4*4+2) * HK],
                      fmaf(w4.w, wvc[(size_t)(j4*4+3) * HK], acc))));
            }
            float inv = (p == 0) ? inv0 : (p == 1) ? inv1
                      : (p == 2) ? inv2 : inv3;
            obt[p * 64 + lane] = acc * inv;           // coalesced
        }
    }
}

extern "C" void kernel_launch(void* const* d_in, const int* in_sizes, int n_in,
                              void* d_out, int out_size, void* d_ws, size_t ws_size,
                              hipStream_t stream) {
    const float* q_x  = (const float*)d_in[0];   // [16,128,256]
    const float* kv_x = (const float*)d_in[1];   // [16,128,127,64]
    const float* Wq   = (const float*)d_in[2];   // [256,256]
    const float* Wk   = (const float*)d_in[3];   // [64,256]
    const float* Wv   = (const float*)d_in[4];   // [64,256]
    float* out = (float*)d_out;                  // [16,128,256] f32

    float* qk = (float*)d_ws;                    // BT*HK floats = 2 MB

    qk_fused <<<BT / 4, 256, 0, stream>>>(q_x, Wq, Wk, qk);
    attn_fused<<<BT / 4, 256, 0, stream>>>(kv_x, qk, Wv, out);
}

// Round 21
// 35.562 us; speedup vs baseline: 1.0298x; 1.0298x over previous
//
#include <hip/hip_runtime.h>
#include <math.h>

// Shapes (hard-coded per reference setup_inputs):
//   b=16, t=128, c=t-1=127, kv_dim=k=64, h=4, q_dim=256
#define Bdim 16
#define Tdim 128
#define Cdim 127
#define Hdim 4
#define QD   256
#define HK   256   // h*k
#define BT   (Bdim * Tdim)

// ---- DPP quad ops (VALU pipe) ----
#define DPP_XOR1 0xB1   // quad_perm [1,0,3,2] : lane^1
#define DPP_XOR2 0x4E   // quad_perm [2,3,0,1] : lane^2
template<int CTRL>
__device__ __forceinline__ float dpp_movf(float x) {
    return __int_as_float(__builtin_amdgcn_update_dpp(
        0, __float_as_int(x), CTRL, 0xF, 0xF, true));
}
__device__ __forceinline__ float dot4(float4 a, float4 b, float s) {
    return fmaf(a.x, b.x, fmaf(a.y, b.y, fmaf(a.z, b.z, fmaf(a.w, b.w, s))));
}
__device__ __forceinline__ float4 fma4(float e, float4 x, float4 v) {
    v.x = fmaf(e, x.x, v.x); v.y = fmaf(e, x.y, v.y);
    v.z = fmaf(e, x.z, v.z); v.w = fmaf(e, x.w, v.w);
    return v;
}
__device__ __forceinline__ float4 add4(float4 a, float4 b) {
    return make_float4(a.x + b.x, a.y + b.y, a.z + b.z, a.w + b.w);
}
__device__ __forceinline__ float4 shfl4(float4 v, int m) {
    return make_float4(__shfl_xor(v.x, m, 64), __shfl_xor(v.y, m, 64),
                       __shfl_xor(v.z, m, 64), __shfl_xor(v.w, m, 64));
}
__device__ __forceinline__ float4 sel4(int c, float4 a, float4 b) {
    return c ? a : b;
}

// ---------------------------------------------------------------------------
// K1: qk[bt, h*64+m] = sum_j (q_x[bt,:] @ Wq)[h*64+j] * Wk[m, h*64+j]
// (measured ~2.4 us including launch gap — unchanged)
__global__ __launch_bounds__(256) void qk_fused(
        const float* __restrict__ q_x,
        const float* __restrict__ Wq,
        const float* __restrict__ Wk,
        float* __restrict__ qk) {
    __shared__ __align__(16) float q_s[4][256];
    __shared__ __align__(16) float p_s[4][4][68];   // [row][head][j] padded
    int RB = blockIdx.x;
    int tid = threadIdx.x;
    {
        int r = tid >> 6, kq = tid & 63;
        *(float4*)&q_s[r][kq*4] =
            *(const float4*)(q_x + (size_t)(RB*4 + r) * QD + kq * 4);
    }
    __syncthreads();

    float acc[4] = {0.f, 0.f, 0.f, 0.f};
    #pragma unroll 4
    for (int i4 = 0; i4 < 64; ++i4) {
        float w0 = Wq[(size_t)(4*i4+0) * HK + tid];   // coalesced, L2-hot
        float w1 = Wq[(size_t)(4*i4+1) * HK + tid];
        float w2 = Wq[(size_t)(4*i4+2) * HK + tid];
        float w3 = Wq[(size_t)(4*i4+3) * HK + tid];
        #pragma unroll
        for (int r = 0; r < 4; ++r) {
            float4 qv = *(const float4*)&q_s[r][i4*4];   // b128 broadcast
            acc[r] = fmaf(qv.x, w0, fmaf(qv.y, w1, fmaf(qv.z, w2, fmaf(qv.w, w3, acc[r]))));
        }
    }
    int h = tid >> 6, m = tid & 63;
    #pragma unroll
    for (int r = 0; r < 4; ++r) p_s[r][h][m] = acc[r];
    __syncthreads();

    const float4* wk4 = (const float4*)(Wk + (size_t)m * HK + h * 64);
    float4 wkr[16];
    #pragma unroll
    for (int j = 0; j < 16; ++j) wkr[j] = wk4[j];       // L2-hot, 64 KB total
    float a2[4] = {0.f, 0.f, 0.f, 0.f};
    #pragma unroll
    for (int j4 = 0; j4 < 16; ++j4) {
        #pragma unroll
        for (int r = 0; r < 4; ++r) {
            float4 pv = *(const float4*)&p_s[r][h][j4*4];  // wave-uniform bcast
            a2[r] = fmaf(pv.x, wkr[j4].x, fmaf(pv.y, wkr[j4].y,
                    fmaf(pv.z, wkr[j4].z, fmaf(pv.w, wkr[j4].w, a2[r]))));
        }
    }
    #pragma unroll
    for (int r = 0; r < 4; ++r)
        qk[(size_t)(RB*4 + r) * HK + tid] = a2[r];      // coalesced
}

// ---------------------------------------------------------------------------
// K2: attn_fused — r19 single-pass core, split 2-HEADS-PER-WAVE to halve
// VGPR (Q 16->8 f4, V 16->8 f4, ~116 VGPR) -> __launch_bounds__(256,4) =
// 16 waves/CU, DOUBLE the request streams of r19/r20 at the same 64-
// distinct-lines-per-instruction coverage. The two waves of a bt (same
// block, adjacent) read the same rows ~simultaneously: second wave hits
// L1/L2, HBM traffic stays one-pass. Tests whether the ~2.2 TB/s read wall
// is per-wave request tracking (then ~2x BW) or per-CU (then flat).
// Single barrier, placed AFTER all global loads; fused V-proj epilogue.
__global__ __launch_bounds__(256, 4) void attn_fused(
        const float* __restrict__ kv_x,
        const float* __restrict__ qk_g,
        const float* __restrict__ Wv,
        float* __restrict__ out) {
    __shared__ __align__(16) float4 wx_s[2][4][16];  // [slot][head][chunk] 2KB
    __shared__ float dn_s[2][4];
    int tid = threadIdx.x;
    int wv = tid >> 6, lane = tid & 63;
    int slot = wv >> 1;           // which bt of this block
    int hp   = wv & 1;            // head-pair: heads 2hp, 2hp+1
    int bt = blockIdx.x * 2 + slot;
    int r  = lane >> 2;           // row-slot 0..15
    int jq = lane & 3;            // quarter of the row
    const float* Xr = kv_x + (size_t)bt * (Cdim * 64);

    // this wave's 2 heads, quarter jq -> 8 float4 regs
    const float4* qb = (const float4*)(qk_g + (size_t)bt * HK);
    float4 Q00 = qb[(2*hp+0)*16 + jq*4 + 0], Q01 = qb[(2*hp+0)*16 + jq*4 + 1],
           Q02 = qb[(2*hp+0)*16 + jq*4 + 2], Q03 = qb[(2*hp+0)*16 + jq*4 + 3];
    float4 Q10 = qb[(2*hp+1)*16 + jq*4 + 0], Q11 = qb[(2*hp+1)*16 + jq*4 + 1],
           Q12 = qb[(2*hp+1)*16 + jq*4 + 2], Q13 = qb[(2*hp+1)*16 + jq*4 + 3];

    float4 V00={0,0,0,0},V01={0,0,0,0},V02={0,0,0,0},V03={0,0,0,0};
    float4 V10={0,0,0,0},V11={0,0,0,0},V12={0,0,0,0},V13={0,0,0,0};
    float d0=0.f, d1=0.f;
    float4 A0, A1, A2, A3, B0, B1, B2, B3;

#define LOADR(P0,P1,P2,P3,KK) do {                                           \
    int c_ = 16*(KK) + r;                                                    \
    const float4* xp_ = (const float4*)(Xr + (size_t)((c_ < Cdim) ? c_ : 0)  \
                                        * 64) + jq * 4;                      \
    P0 = xp_[0]; P1 = xp_[1]; P2 = xp_[2]; P3 = xp_[3];                      \
} while (0)

#define COMP(P0,P1,P2,P3,KK) do {                                            \
    float s0 = dot4(Q00,P0,0.f); s0 = dot4(Q01,P1,s0);                       \
    s0 = dot4(Q02,P2,s0); s0 = dot4(Q03,P3,s0);                              \
    float s1 = dot4(Q10,P0,0.f); s1 = dot4(Q11,P1,s1);                       \
    s1 = dot4(Q12,P2,s1); s1 = dot4(Q13,P3,s1);                              \
    s0 += dpp_movf<DPP_XOR1>(s0); s0 += dpp_movf<DPP_XOR2>(s0);              \
    s1 += dpp_movf<DPP_XOR1>(s1); s1 += dpp_movf<DPP_XOR2>(s1);              \
    bool vld_ = (16*(KK) + r) < Cdim;                                        \
    float e0 = vld_ ? __expf(s0 * 0.125f) : 0.f;                             \
    float e1 = vld_ ? __expf(s1 * 0.125f) : 0.f;                             \
    d0 += e0; d1 += e1;                                                      \
    V00=fma4(e0,P0,V00); V01=fma4(e0,P1,V01);                                \
    V02=fma4(e0,P2,V02); V03=fma4(e0,P3,V03);                                \
    V10=fma4(e1,P0,V10); V11=fma4(e1,P1,V11);                                \
    V12=fma4(e1,P2,V12); V13=fma4(e1,P3,V13);                                \
} while (0)

    // 2-deep hand pipeline (8 b128 in flight per lane)
    LOADR(A0,A1,A2,A3,0);
    LOADR(B0,B1,B2,B3,1);
    COMP (A0,A1,A2,A3,0);
    LOADR(A0,A1,A2,A3,2);
    COMP (B0,B1,B2,B3,1);
    LOADR(B0,B1,B2,B3,3);
    COMP (A0,A1,A2,A3,2);
    LOADR(A0,A1,A2,A3,4);
    COMP (B0,B1,B2,B3,3);
    LOADR(B0,B1,B2,B3,5);
    COMP (A0,A1,A2,A3,4);
    LOADR(A0,A1,A2,A3,6);
    COMP (B0,B1,B2,B3,5);
    LOADR(B0,B1,B2,B3,7);
    COMP (A0,A1,A2,A3,6);
    COMP (B0,B1,B2,B3,7);
#undef LOADR
#undef COMP

    // ---- splitting butterfly over r bits (lane bits 2-5) ----
    int r0 = (lane >> 2) & 1, r1 = (lane >> 3) & 1;
    int r2 = (lane >> 4) & 1, r3 = (lane >> 5) & 1;
    // Round 1 (xor 4): keep q with (q&1)==r0
    float4 K00 = add4(sel4(r0, V01, V00), shfl4(sel4(r0, V00, V01), 4));
    float4 K01 = add4(sel4(r0, V03, V02), shfl4(sel4(r0, V02, V03), 4));
    float4 K10 = add4(sel4(r0, V11, V10), shfl4(sel4(r0, V10, V11), 4));
    float4 K11 = add4(sel4(r0, V13, V12), shfl4(sel4(r0, V12, V13), 4));
    // Round 2 (xor 8): keep p==r1 -> per head one chunk, qo=(r1<<1)|r0
    float4 L0 = add4(sel4(r1, K01, K00), shfl4(sel4(r1, K00, K01), 8));
    float4 L1 = add4(sel4(r1, K11, K10), shfl4(sel4(r1, K10, K11), 8));
    // Round 3 (xor 16): split the 2 heads by r2
    float4 M = add4(sel4(r2, L1, L0), shfl4(sel4(r2, L0, L1), 16));
    // Round 4 (xor 32): plain sum (r3 copies identical)
    float4 F = add4(M, shfl4(M, 32));

    // denom butterfly over r bits
    #pragma unroll
    for (int m = 4; m <= 32; m <<= 1) {
        d0 += __shfl_xor(d0, m, 64);
        d1 += __shfl_xor(d1, m, 64);
    }

    int H  = 2*hp + r2;
    int qo = (r1 << 1) | r0;
    if (r3 == 0) wx_s[slot][H][jq * 4 + qo] = F;   // 32 lanes, 32 chunks
    if (lane == 0) { dn_s[slot][2*hp+0] = d0; dn_s[slot][2*hp+1] = d1; }
    __syncthreads();   // single barrier, after ALL global loads are consumed

    // ---- fused V-projection epilogue: 2 passes (one per slot) ----
    #pragma unroll
    for (int s = 0; s < 2; ++s) {
        int col = tid;                   // 0..255 = h*64 + k
        int h = col >> 6;                // wave-uniform
        float inv = 1.f / dn_s[s][h];
        const float* wvc = Wv + col;     // Wv[j*HK + col], coalesced, L2-hot
        float acc = 0.f;
        #pragma unroll
        for (int j4 = 0; j4 < 16; ++j4) {
            float4 w4 = wx_s[s][h][j4];  // wave-uniform broadcast
            acc = fmaf(w4.x, wvc[(size_t)(j4*4+0) * HK],
                  fmaf(w4.y, wvc[(size_t)(j4*4+1) * HK],
                  fmaf(w4.z, wvc[(size_t)(j4*4+2) * HK],
                  fmaf(w4.w, wvc[(size_t)(j4*4+3) * HK], acc))));
        }
        out[(size_t)(blockIdx.x * 2 + s) * HK + col] = acc * inv;
    }
}

extern "C" void kernel_launch(void* const* d_in, const int* in_sizes, int n_in,
                              void* d_out, int out_size, void* d_ws, size_t ws_size,
                              hipStream_t stream) {
    const float* q_x  = (const float*)d_in[0];   // [16,128,256]
    const float* kv_x = (const float*)d_in[1];   // [16,128,127,64]
    const float* Wq   = (const float*)d_in[2];   // [256,256]
    const float* Wk   = (const float*)d_in[3];   // [64,256]
    const float* Wv   = (const float*)d_in[4];   // [64,256]
    float* out = (float*)d_out;                  // [16,128,256] f32

    float* qk = (float*)d_ws;                    // BT*HK floats = 2 MB

    qk_fused <<<BT / 4, 256, 0, stream>>>(q_x, Wq, Wk, qk);
    attn_fused<<<BT / 2, 256, 0, stream>>>(kv_x, qk, Wv, out);
}